// Round 1
// baseline (320.286 us; speedup 1.0000x reference)
//
#include <hip/hip_runtime.h>

#define B 64
#define S 1024
#define U 512
#define H 512
#define D 512

__device__ __forceinline__ float tanh_fast(float x) {
    // tanh(x) = 1 - 2/(exp(2x)+1); __expf handles the +/-inf saturation naturally.
    float e = __expf(2.0f * x);
    return 1.0f - 2.0f / (e + 1.0f);
}

// Kernel 1: dec_attn[b,u] = b_dec[u] + sum_d dec_state[b,d] * W_dec[d,u]
// 2 blocks per batch row (256 u each); dec_state row staged in LDS.
__global__ __launch_bounds__(256) void k_decproj(
    const float* __restrict__ dec_state, const float* __restrict__ W_dec,
    const float* __restrict__ b_dec, float* __restrict__ dec_attn)
{
    __shared__ float ds[D];
    int b = blockIdx.x >> 1;
    int u = (blockIdx.x & 1) * 256 + threadIdx.x;
    ds[threadIdx.x]       = dec_state[b * D + threadIdx.x];
    ds[threadIdx.x + 256] = dec_state[b * D + threadIdx.x + 256];
    __syncthreads();
    float acc = b_dec[u];
    #pragma unroll 8
    for (int d = 0; d < D; ++d)
        acc = fmaf(ds[d], W_dec[d * U + u], acc);
    dec_attn[b * U + u] = acc;
}

// Kernel 2: one wave64 per (b,s) row.
// score[b,s] = sum_u tanh(enc_attn[b,s,u] + cov[b,s]*W_cov[u] + dec_attn[b,u]) * w_attn[u]
__global__ __launch_bounds__(256) void k_scores(
    const float4* __restrict__ enc_attn4, const float* __restrict__ cov,
    const float4* __restrict__ dec_attn4, const float4* __restrict__ Wcov4,
    const float4* __restrict__ wattn4, float* __restrict__ scores)
{
    int row  = blockIdx.x * 4 + (threadIdx.x >> 6);   // [0, B*S)
    int lane = threadIdx.x & 63;
    int b    = row >> 10;
    float c  = cov[row];
    size_t base = (size_t)row * 128;                  // 128 float4 per row
    float acc = 0.0f;
    #pragma unroll
    for (int it = 0; it < 2; ++it) {
        int i = lane + it * 64;
        float4 ea = enc_attn4[base + i];
        float4 wc = Wcov4[i];
        float4 da = dec_attn4[b * 128 + i];
        float4 wa = wattn4[i];
        acc += tanh_fast(ea.x + c * wc.x + da.x) * wa.x;
        acc += tanh_fast(ea.y + c * wc.y + da.y) * wa.y;
        acc += tanh_fast(ea.z + c * wc.z + da.z) * wa.z;
        acc += tanh_fast(ea.w + c * wc.w + da.w) * wa.w;
    }
    #pragma unroll
    for (int off = 32; off >= 1; off >>= 1)
        acc += __shfl_xor(acc, off, 64);
    if (lane == 0) scores[row] = acc;
}

// Kernel 3: softmax over S per batch, in place (scores -> attn) in d_out.
// Also zero-inits the c_vector region (d_out is poisoned before every call).
__global__ __launch_bounds__(256) void k_softmax(
    float* __restrict__ inout, float* __restrict__ cvec)
{
    __shared__ float red[4];
    int b = blockIdx.x;
    int t = threadIdx.x;
    cvec[b * H + t]       = 0.0f;
    cvec[b * H + t + 256] = 0.0f;
    float v[4];
    float m = -1e30f;
    #pragma unroll
    for (int i = 0; i < 4; ++i) {
        v[i] = inout[b * S + t + i * 256];
        m = fmaxf(m, v[i]);
    }
    #pragma unroll
    for (int off = 32; off >= 1; off >>= 1)
        m = fmaxf(m, __shfl_xor(m, off, 64));
    int wave = t >> 6, lane = t & 63;
    if (lane == 0) red[wave] = m;
    __syncthreads();
    m = fmaxf(fmaxf(red[0], red[1]), fmaxf(red[2], red[3]));
    float sum = 0.0f;
    #pragma unroll
    for (int i = 0; i < 4; ++i) { v[i] = __expf(v[i] - m); sum += v[i]; }
    #pragma unroll
    for (int off = 32; off >= 1; off >>= 1)
        sum += __shfl_xor(sum, off, 64);
    __syncthreads();
    if (lane == 0) red[wave] = sum;
    __syncthreads();
    float inv = 1.0f / (red[0] + red[1] + red[2] + red[3]);
    #pragma unroll
    for (int i = 0; i < 4; ++i)
        inout[b * S + t + i * 256] = v[i] * inv;
}

// Kernel 4: c_vector[b,h] = sum_s enc_output[b,s,h] * attn[b,s]
// grid (16 s-chunks, 64 b); each block: 2 s-lanes x 128 float4 h-lanes,
// LDS pair-reduce, then atomicAdd 16 partials per output element.
__global__ __launch_bounds__(256) void k_cvec(
    const float4* __restrict__ enc4, const float* __restrict__ attn,
    float* __restrict__ cvec)
{
    __shared__ float4 part[128];
    int tid = threadIdx.x;
    int hi  = tid & 127;
    int sp  = tid >> 7;
    int b   = blockIdx.y;
    int s0  = blockIdx.x * 64;
    float4 acc = make_float4(0.f, 0.f, 0.f, 0.f);
    for (int s = s0 + sp; s < s0 + 64; s += 2) {
        float a  = attn[b * S + s];
        float4 v = enc4[(size_t)(b * S + s) * 128 + hi];
        acc.x = fmaf(v.x, a, acc.x);
        acc.y = fmaf(v.y, a, acc.y);
        acc.z = fmaf(v.z, a, acc.z);
        acc.w = fmaf(v.w, a, acc.w);
    }
    if (sp == 1) part[hi] = acc;
    __syncthreads();
    if (sp == 0) {
        float4 o = part[hi];
        float* dst = cvec + b * H + hi * 4;
        atomicAdd(dst + 0, acc.x + o.x);
        atomicAdd(dst + 1, acc.y + o.y);
        atomicAdd(dst + 2, acc.z + o.z);
        atomicAdd(dst + 3, acc.w + o.w);
    }
}

extern "C" void kernel_launch(void* const* d_in, const int* in_sizes, int n_in,
                              void* d_out, int out_size, void* d_ws, size_t ws_size,
                              hipStream_t stream) {
    const float* enc_output = (const float*)d_in[0];   // [B,S,H]
    const float* enc_attn   = (const float*)d_in[1];   // [B,S,U]
    const float* cov        = (const float*)d_in[2];   // [B,S]
    const float* dec_state  = (const float*)d_in[3];   // [B,D]
    const float* W_dec      = (const float*)d_in[4];   // [D,U]
    const float* b_dec      = (const float*)d_in[5];   // [U]
    const float* W_cov      = (const float*)d_in[6];   // [1,U]
    const float* w_attn     = (const float*)d_in[7];   // [U,1]

    float* out      = (float*)d_out;     // [0,B*S): attn (scores first), [B*S, B*S+B*H): c_vector
    float* dec_attn = (float*)d_ws;      // B*U floats = 128 KB scratch

    k_decproj<<<B * 2, 256, 0, stream>>>(dec_state, W_dec, b_dec, dec_attn);
    k_scores<<<(B * S) / 4, 256, 0, stream>>>(
        (const float4*)enc_attn, cov, (const float4*)dec_attn,
        (const float4*)W_cov, (const float4*)w_attn, out);
    k_softmax<<<B, 256, 0, stream>>>(out, out + B * S);
    k_cvec<<<dim3(16, B), 256, 0, stream>>>(
        (const float4*)enc_output, out, out + B * S);
}

// Round 2
// 289.168 us; speedup vs baseline: 1.1076x; 1.1076x over previous
//
#include <hip/hip_runtime.h>

#define B 64
#define S 1024
#define U 512
#define H 512
#define D 512

typedef float v4f __attribute__((ext_vector_type(4)));

__device__ __forceinline__ float tanh_fast(float x) {
    // tanh(x) = 1 - 2/(exp(2x)+1); __expf saturates correctly at +/-inf.
    float e = __expf(2.0f * x);
    return 1.0f - 2.0f / (e + 1.0f);
}

// Kernel 1: dec_attn[b,u] = b_dec[u] + sum_d dec_state[b,d]*W_dec[d,u]
// 4 blocks per b (128 u each), D split in halves across the block + LDS reduce
// -> 256 blocks (vs 128 before: full-chip, half the load-chain length).
// Also zero-inits the c_vector region of d_out (poisoned 0xAA by harness).
__global__ __launch_bounds__(256) void k_prep(
    const float* __restrict__ dec_state, const float* __restrict__ W_dec,
    const float* __restrict__ b_dec, float* __restrict__ dec_attn,
    float* __restrict__ cvec)
{
    __shared__ float ds[D];
    __shared__ float part[128];
    int tid = threadIdx.x;
    int b   = blockIdx.x >> 2;
    int q   = blockIdx.x & 3;
    int ul  = tid & 127;
    int dh  = tid >> 7;
    int u   = q * 128 + ul;

    int g = blockIdx.x * 256 + tid;           // 65536 threads, 32768 cvec elems
    if (g < B * H) cvec[g] = 0.0f;

    ds[tid]       = dec_state[b * D + tid];
    ds[tid + 256] = dec_state[b * D + tid + 256];
    __syncthreads();

    float acc = 0.0f;
    int d0 = dh * 256;
    #pragma unroll 8
    for (int d = d0; d < d0 + 256; ++d)
        acc = fmaf(ds[d], W_dec[d * U + u], acc);

    if (dh == 1) part[ul] = acc;
    __syncthreads();
    if (dh == 0)
        dec_attn[b * U + u] = acc + part[ul] + b_dec[u];
}

// Kernel 2: one wave64 per (b,s) row.
// score[b,s] = sum_u tanh(enc_attn[b,s,u] + cov[b,s]*W_cov[u] + dec_attn[b,u]) * w_attn[u]
// Raw scores go to ws; softmax is recomputed (cheaply) inside k_attn_cvec.
__global__ __launch_bounds__(256) void k_scores(
    const v4f* __restrict__ enc_attn4, const float* __restrict__ cov,
    const v4f* __restrict__ dec_attn4, const v4f* __restrict__ Wcov4,
    const v4f* __restrict__ wattn4, float* __restrict__ scores)
{
    int row  = blockIdx.x * 4 + (threadIdx.x >> 6);   // [0, B*S)
    int lane = threadIdx.x & 63;
    int b    = row >> 10;
    size_t base = (size_t)row * 128;                  // 128 v4f per row

    // Issue the two streaming loads first (nontemporal: read-once data).
    v4f ea0 = __builtin_nontemporal_load(enc_attn4 + base + lane);
    v4f ea1 = __builtin_nontemporal_load(enc_attn4 + base + lane + 64);
    float c = cov[row];
    v4f wc0 = Wcov4[lane],           wc1 = Wcov4[lane + 64];
    v4f da0 = dec_attn4[b * 128 + lane], da1 = dec_attn4[b * 128 + lane + 64];
    v4f wa0 = wattn4[lane],          wa1 = wattn4[lane + 64];

    float acc = 0.0f;
    acc += tanh_fast(ea0.x + c * wc0.x + da0.x) * wa0.x;
    acc += tanh_fast(ea0.y + c * wc0.y + da0.y) * wa0.y;
    acc += tanh_fast(ea0.z + c * wc0.z + da0.z) * wa0.z;
    acc += tanh_fast(ea0.w + c * wc0.w + da0.w) * wa0.w;
    acc += tanh_fast(ea1.x + c * wc1.x + da1.x) * wa1.x;
    acc += tanh_fast(ea1.y + c * wc1.y + da1.y) * wa1.y;
    acc += tanh_fast(ea1.z + c * wc1.z + da1.z) * wa1.z;
    acc += tanh_fast(ea1.w + c * wc1.w + da1.w) * wa1.w;

    #pragma unroll
    for (int off = 32; off >= 1; off >>= 1)
        acc += __shfl_xor(acc, off, 64);
    if (lane == 0) scores[row] = acc;
}

// Kernel 3 (fused softmax + context vector):
// Each block (s-chunk x, batch b) recomputes softmax stats over scores[b,:]
// (4 KB from L2, 16x redundant = free), writes attn (block x==0 only), and
// accumulates c_vector partials for its 64-row chunk via atomicAdd.
__global__ __launch_bounds__(256) void k_attn_cvec(
    const v4f* __restrict__ enc4, const float* __restrict__ scores,
    float* __restrict__ attn_out, float* __restrict__ cvec)
{
    __shared__ float red[4];
    __shared__ float a_lds[64];
    __shared__ v4f  part[128];
    int tid = threadIdx.x;
    int b   = blockIdx.y;
    int s0  = blockIdx.x * 64;

    float sc[4];
    #pragma unroll
    for (int i = 0; i < 4; ++i) sc[i] = scores[b * S + tid + i * 256];

    float m = fmaxf(fmaxf(sc[0], sc[1]), fmaxf(sc[2], sc[3]));
    #pragma unroll
    for (int off = 32; off >= 1; off >>= 1)
        m = fmaxf(m, __shfl_xor(m, off, 64));
    int wave = tid >> 6, lane = tid & 63;
    if (lane == 0) red[wave] = m;
    __syncthreads();
    m = fmaxf(fmaxf(red[0], red[1]), fmaxf(red[2], red[3]));

    float e[4], sum = 0.0f;
    #pragma unroll
    for (int i = 0; i < 4; ++i) { e[i] = __expf(sc[i] - m); sum += e[i]; }
    #pragma unroll
    for (int off = 32; off >= 1; off >>= 1)
        sum += __shfl_xor(sum, off, 64);
    __syncthreads();
    if (lane == 0) red[wave] = sum;
    __syncthreads();
    float inv = 1.0f / (red[0] + red[1] + red[2] + red[3]);

    if (blockIdx.x == 0) {
        #pragma unroll
        for (int i = 0; i < 4; ++i)
            attn_out[b * S + tid + i * 256] = e[i] * inv;
    }

    if (tid < 64)
        a_lds[tid] = __expf(scores[b * S + s0 + tid] - m) * inv;
    __syncthreads();

    int hi = tid & 127;        // v4f column, wave-contiguous
    int sp = tid >> 7;         // s parity (wave-uniform)
    v4f acc = {0.f, 0.f, 0.f, 0.f};
    #pragma unroll 8
    for (int i = 0; i < 32; ++i) {
        int s   = s0 + sp + 2 * i;
        float a = a_lds[sp + 2 * i];
        v4f  v  = __builtin_nontemporal_load(enc4 + (size_t)(b * S + s) * 128 + hi);
        acc.x = fmaf(v.x, a, acc.x);
        acc.y = fmaf(v.y, a, acc.y);
        acc.z = fmaf(v.z, a, acc.z);
        acc.w = fmaf(v.w, a, acc.w);
    }

    if (sp == 1) part[hi] = acc;
    __syncthreads();
    if (sp == 0) {
        v4f o = part[hi];
        float* dst = cvec + b * H + hi * 4;
        atomicAdd(dst + 0, acc.x + o.x);
        atomicAdd(dst + 1, acc.y + o.y);
        atomicAdd(dst + 2, acc.z + o.z);
        atomicAdd(dst + 3, acc.w + o.w);
    }
}

extern "C" void kernel_launch(void* const* d_in, const int* in_sizes, int n_in,
                              void* d_out, int out_size, void* d_ws, size_t ws_size,
                              hipStream_t stream) {
    const float* enc_output = (const float*)d_in[0];   // [B,S,H]
    const float* enc_attn   = (const float*)d_in[1];   // [B,S,U]
    const float* cov        = (const float*)d_in[2];   // [B,S]
    const float* dec_state  = (const float*)d_in[3];   // [B,D]
    const float* W_dec      = (const float*)d_in[4];   // [D,U]
    const float* b_dec      = (const float*)d_in[5];   // [U]
    const float* W_cov      = (const float*)d_in[6];   // [1,U]
    const float* w_attn     = (const float*)d_in[7];   // [U,1]

    float* out      = (float*)d_out;       // [0,B*S): attn, [B*S,+B*H): c_vector
    float* dec_attn = (float*)d_ws;        // B*U floats
    float* scores   = (float*)d_ws + B * U;// B*S floats

    k_prep<<<B * 4, 256, 0, stream>>>(dec_state, W_dec, b_dec, dec_attn, out + B * S);
    k_scores<<<(B * S) / 4, 256, 0, stream>>>(
        (const v4f*)enc_attn, cov, (const v4f*)dec_attn,
        (const v4f*)W_cov, (const v4f*)w_attn, scores);
    k_attn_cvec<<<dim3(16, B), 256, 0, stream>>>(
        (const v4f*)enc_output, scores, out, out + B * S);
}